// Round 1
// baseline (429.708 us; speedup 1.0000x reference)
//
#include <hip/hip_runtime.h>
#include <cstdint>

#define S_LEN 1024
#define C_DIM 2048
#define NH    16
#define NHK   4
#define HD    128
#define ROT   32
#define SCALE 0.08838834764831845f  // 1/sqrt(128)

typedef __bf16 bf16x8 __attribute__((ext_vector_type(8)));
typedef float floatx4 __attribute__((ext_vector_type(4)));

__device__ __forceinline__ unsigned short f2bf(float f) {
  union { float f; uint32_t u; } x; x.f = f;
  uint32_t r = (x.u + 0x7fffu + ((x.u >> 16) & 1u)) >> 16;
  return (unsigned short)r;
}

__device__ __forceinline__ void async_copy16(const unsigned short* g, unsigned short* l) {
  __builtin_amdgcn_global_load_lds(
      (const __attribute__((address_space(1))) void*)g,
      (__attribute__((address_space(3))) void*)l,
      16, 0, 0);
}

// ---------------- cast f32 -> bf16 (vectorized) ----------------
__global__ void cast_bf16_kernel(const float* __restrict__ in,
                                 unsigned short* __restrict__ out, int n4) {
  int i = blockIdx.x * blockDim.x + threadIdx.x;
  if (i >= n4) return;
  float4 v = ((const float4*)in)[i];
  ushort4 o;
  o.x = f2bf(v.x); o.y = f2bf(v.y); o.z = f2bf(v.z); o.w = f2bf(v.w);
  ((ushort4*)out)[i] = o;
}

// ---------------- transpose + cast x (C,S) -> xT (S,C) bf16 ----------------
__global__ __launch_bounds__(256)
void transpose_cast_x_kernel(const float* __restrict__ x, unsigned short* __restrict__ xT) {
  __shared__ float t[32][33];
  int st = blockIdx.x, ct = blockIdx.y;
  int c = threadIdx.x & 31, rq = threadIdx.x >> 5;
#pragma unroll
  for (int i = 0; i < 4; ++i) {
    int r = rq + i * 8;
    t[r][c] = x[(size_t)(ct * 32 + r) * S_LEN + st * 32 + c];
  }
  __syncthreads();
#pragma unroll
  for (int i = 0; i < 4; ++i) {
    int r = rq + i * 8;  // s within tile
    xT[(size_t)(st * 32 + r) * C_DIM + ct * 32 + c] = f2bf(t[c][r]);
  }
}

// ---------------- GEMM: C(M,N) f32 = A(M,K)bf16 @ BT(N,K)bf16^T ----------------
// 128x128 tile, BK=64, 4 waves each 64x64 (4x4 of 16x16x32 MFMA)
__global__ __launch_bounds__(256)
void gemm_bt_kernel(const unsigned short* __restrict__ A,
                    const unsigned short* __restrict__ BT,
                    float* __restrict__ C, int M, int N, int K) {
  __shared__ unsigned short Asm[128 * 64];
  __shared__ unsigned short Bsm[128 * 64];
  int tid = threadIdx.x;
  int wave = tid >> 6, lane = tid & 63;
  int m0 = blockIdx.y * 128, n0 = blockIdx.x * 128;
  int l16 = lane & 15, quad = lane >> 4;
  int wm = (wave & 1) * 64, wn = (wave >> 1) * 64;
  int srow = wave * 8 + (lane >> 3);   // staging row within 32-row chunk
  int scol = (lane & 7) * 8;           // staging element col (8 bf16 = 16B)
  const unsigned short* Ag = A + (size_t)m0 * K;
  const unsigned short* Bg = BT + (size_t)n0 * K;
  floatx4 acc[4][4];
#pragma unroll
  for (int mi = 0; mi < 4; ++mi)
#pragma unroll
    for (int ni = 0; ni < 4; ++ni) acc[mi][ni] = (floatx4)0.f;

  for (int kt = 0; kt < K; kt += 64) {
#pragma unroll
    for (int i = 0; i < 4; ++i) {
      async_copy16(Ag + (size_t)(i * 32 + srow) * K + kt + scol, Asm + (i * 32 + wave * 8) * 64);
      async_copy16(Bg + (size_t)(i * 32 + srow) * K + kt + scol, Bsm + (i * 32 + wave * 8) * 64);
    }
    __syncthreads();
#pragma unroll
    for (int kb = 0; kb < 2; ++kb) {
      bf16x8 af[4], bfr[4];
#pragma unroll
      for (int mi = 0; mi < 4; ++mi)
        af[mi] = *(const bf16x8*)&Asm[(wm + mi * 16 + l16) * 64 + kb * 32 + quad * 8];
#pragma unroll
      for (int ni = 0; ni < 4; ++ni)
        bfr[ni] = *(const bf16x8*)&Bsm[(wn + ni * 16 + l16) * 64 + kb * 32 + quad * 8];
#pragma unroll
      for (int mi = 0; mi < 4; ++mi)
#pragma unroll
        for (int ni = 0; ni < 4; ++ni)
          acc[mi][ni] = __builtin_amdgcn_mfma_f32_16x16x32_bf16(af[mi], bfr[ni], acc[mi][ni], 0, 0, 0);
    }
    __syncthreads();
  }
#pragma unroll
  for (int mi = 0; mi < 4; ++mi) {
#pragma unroll
    for (int r = 0; r < 4; ++r) {
      int row = m0 + wm + mi * 16 + quad * 4 + r;
      float* Cp = C + (size_t)row * N + n0 + wn;
#pragma unroll
      for (int ni = 0; ni < 4; ++ni)
        Cp[ni * 16 + l16] = acc[mi][ni][r];
    }
  }
}

// ---------------- RMSNorm + RoPE, transpose (rows,S) -> (h,S,D) f32 ----------------
__global__ __launch_bounds__(256)
void norm_rope_kernel(const float* __restrict__ raw, int head_rows,
                      const float* __restrict__ w,
                      const int* __restrict__ pos_ids,
                      const float* __restrict__ cosc, const float* __restrict__ sinc,
                      float* __restrict__ out) {
  __shared__ float tile[128][65];
  __shared__ float psum[4][64];
  __shared__ float rnorm[64];
  int h = blockIdx.x, st = blockIdx.y;
  int s0 = st * 64;
  int tid = threadIdx.x;
  const float* base = raw + (size_t)(h * head_rows) * S_LEN + s0;
  {
    int so = tid & 63, dq = tid >> 6;
#pragma unroll
    for (int it = 0; it < 32; ++it) {
      int d = it * 4 + dq;
      tile[d][so] = base[(size_t)d * S_LEN + so];
    }
  }
  __syncthreads();
  {
    int s = tid & 63, part = tid >> 6;
    float sum = 0.f;
    for (int dd = 0; dd < 32; ++dd) {
      float v = tile[part * 32 + dd][s];
      sum += v * v;
    }
    psum[part][s] = sum;
  }
  __syncthreads();
  if (tid < 64) {
    float tot = psum[0][tid] + psum[1][tid] + psum[2][tid] + psum[3][tid];
    rnorm[tid] = rsqrtf(tot * (1.0f / 128.0f) + 1e-6f);
  }
  __syncthreads();
  {
    int d = tid & 127, sr = tid >> 7;
    float wd = 1.0f + w[d];
    int dp = (d < 16) ? d + 16 : d - 16;
    float wdp = (d < ROT) ? (1.0f + w[dp]) : 0.f;
    for (int it = 0; it < 32; ++it) {
      int s = it * 2 + sr;
      float r = rnorm[s];
      float val = tile[d][s] * r * wd;
      if (d < ROT) {
        int pos = pos_ids[s0 + s];
        float cv = cosc[pos * ROT + d];
        float sv = sinc[pos * ROT + d];
        float partner = tile[dp][s] * r * wdp;
        val = val * cv + ((d < 16) ? -partner : partner) * sv;
      }
      out[((size_t)(h * S_LEN + s0 + s)) * HD + d] = val;
    }
  }
}

// ---------------- transpose (rows,S) -> (h,S,D), optional sigmoid ----------------
__global__ __launch_bounds__(256)
void transpose_head_kernel(const float* __restrict__ raw, int head_rows, int row_off,
                           int do_sigmoid, float* __restrict__ out) {
  __shared__ float t[32][33];
  int st = blockIdx.x;  // s tile
  int dt = blockIdx.y;  // d tile
  int h = blockIdx.z;
  int c = threadIdx.x & 31, rq = threadIdx.x >> 5;
  const float* base = raw + (size_t)(h * head_rows + row_off + dt * 32) * S_LEN + st * 32;
#pragma unroll
  for (int i = 0; i < 4; ++i) {
    int r = rq + i * 8;
    t[r][c] = base[(size_t)r * S_LEN + c];
  }
  __syncthreads();
#pragma unroll
  for (int i = 0; i < 4; ++i) {
    int r = rq + i * 8;  // s within tile
    float v = t[c][r];
    if (do_sigmoid) v = 1.0f / (1.0f + __expf(-v));
    out[((size_t)(h * S_LEN + st * 32 + r)) * HD + dt * 32 + c] = v;
  }
}

// ---------------- flash attention (f32), 16 queries/block, 64-key tiles ----------------
__global__ __launch_bounds__(256)
void attn_kernel(const float* __restrict__ qn, const float* __restrict__ kn,
                 const float* __restrict__ vt, const float* __restrict__ sg,
                 unsigned short* __restrict__ outT) {
  __shared__ float qs[16][132];
  __shared__ float kv[64][132];
  __shared__ float ps[16][68];
  __shared__ float mrow[16], lrow[16], arow[16];
  int h = blockIdx.x, st = blockIdx.y;
  int s0 = st * 16;
  int hk = h >> 2;
  int tid = threadIdx.x;
  // load Q tile
#pragma unroll
  for (int i = 0; i < 8; ++i) {
    int idx = i * 256 + tid;
    int r = idx >> 7, d = idx & 127;
    qs[r][d] = qn[((size_t)(h * S_LEN + s0 + r)) * HD + d];
  }
  if (tid < 16) { mrow[tid] = -1e30f; lrow[tid] = 0.f; }
  float acc[8] = {0, 0, 0, 0, 0, 0, 0, 0};
  int r_own = tid >> 4, dg = tid & 15;
  int tj = tid & 15;
  __syncthreads();
  for (int jt = 0; jt < s0 + 16; jt += 64) {
    // stage K tile
#pragma unroll
    for (int i = 0; i < 8; ++i) {
      int idx = i * 256 + tid;
      int r = idx >> 5, c4 = (idx & 31) * 4;
      *(float4*)&kv[r][c4] = *(const float4*)&kn[((size_t)(hk * S_LEN + jt + r)) * HD + c4];
    }
    __syncthreads();
    // scores: row r_own, j = tj + jj*16
    float a0 = 0, a1 = 0, a2 = 0, a3 = 0;
    for (int d4 = 0; d4 < 128; d4 += 4) {
      float4 qv = *(const float4*)&qs[r_own][d4];
      float4 k0 = *(const float4*)&kv[tj][d4];
      float4 k1 = *(const float4*)&kv[tj + 16][d4];
      float4 k2 = *(const float4*)&kv[tj + 32][d4];
      float4 k3 = *(const float4*)&kv[tj + 48][d4];
      a0 += qv.x * k0.x + qv.y * k0.y + qv.z * k0.z + qv.w * k0.w;
      a1 += qv.x * k1.x + qv.y * k1.y + qv.z * k1.z + qv.w * k1.w;
      a2 += qv.x * k2.x + qv.y * k2.y + qv.z * k2.z + qv.w * k2.w;
      a3 += qv.x * k3.x + qv.y * k3.y + qv.z * k3.z + qv.w * k3.w;
    }
    float sc[4] = {a0, a1, a2, a3};
    int sglob = s0 + r_own;
    float mx = -1e30f;
#pragma unroll
    for (int jj = 0; jj < 4; ++jj) {
      int jg = jt + tj + jj * 16;
      sc[jj] = (jg <= sglob) ? sc[jj] * SCALE : -1e30f;
      mx = fmaxf(mx, sc[jj]);
    }
#pragma unroll
    for (int off = 8; off; off >>= 1) mx = fmaxf(mx, __shfl_xor(mx, off, 16));
    float mold = mrow[r_own];
    float mnew = fmaxf(mold, mx);
    float psv = 0.f;
#pragma unroll
    for (int jj = 0; jj < 4; ++jj) {
      float p = (sc[jj] > -1e29f) ? __expf(sc[jj] - mnew) : 0.0f;
      ps[r_own][tj + jj * 16] = p;
      psv += p;
    }
#pragma unroll
    for (int off = 8; off; off >>= 1) psv += __shfl_xor(psv, off, 16);
    if (tj == 0) {
      float alpha = __expf(mold - mnew);
      mrow[r_own] = mnew;
      lrow[r_own] = lrow[r_own] * alpha + psv;
      arow[r_own] = alpha;
    }
    __syncthreads();
    // stage V tile (reuse kv)
#pragma unroll
    for (int i = 0; i < 8; ++i) {
      int idx = i * 256 + tid;
      int r = idx >> 5, c4 = (idx & 31) * 4;
      *(float4*)&kv[r][c4] = *(const float4*)&vt[((size_t)(hk * S_LEN + jt + r)) * HD + c4];
    }
    __syncthreads();
    float al = arow[r_own];
#pragma unroll
    for (int i = 0; i < 8; ++i) acc[i] *= al;
    int d0 = dg * 8;
    for (int jj = 0; jj < 64; ++jj) {
      int j = (jj + dg) & 63;  // rotate to spread LDS banks
      float p = ps[r_own][j];
      float4 v0 = *(const float4*)&kv[j][d0];
      float4 v1 = *(const float4*)&kv[j][d0 + 4];
      acc[0] += p * v0.x; acc[1] += p * v0.y; acc[2] += p * v0.z; acc[3] += p * v0.w;
      acc[4] += p * v1.x; acc[5] += p * v1.y; acc[6] += p * v1.z; acc[7] += p * v1.w;
    }
    __syncthreads();
  }
  float inv = 1.0f / lrow[r_own];
  int srow = s0 + r_own;
  const float* sgp = &sg[((size_t)(h * S_LEN + srow)) * HD + dg * 8];
  unsigned short* op = &outT[(size_t)srow * (NH * HD) + h * HD + dg * 8];
#pragma unroll
  for (int i = 0; i < 8; ++i)
    op[i] = f2bf(acc[i] * inv * sgp[i]);
}

// ---------------- host launch ----------------
extern "C" void kernel_launch(void* const* d_in, const int* in_sizes, int n_in,
                              void* d_out, int out_size, void* d_ws, size_t ws_size,
                              hipStream_t stream) {
  const float* hs       = (const float*)d_in[0];   // (C, S)
  const float* q_proj_w = (const float*)d_in[1];   // (4096, 2048)
  const float* k_proj_w = (const float*)d_in[2];   // (512, 2048)
  const float* v_proj_w = (const float*)d_in[3];   // (512, 2048)
  const float* o_proj_w = (const float*)d_in[4];   // (2048, 2048)
  const float* q_norm_w = (const float*)d_in[5];
  const float* k_norm_w = (const float*)d_in[6];
  const int*   pos_ids  = (const int*)d_in[9];
  const float* cos_c    = (const float*)d_in[10];
  const float* sin_c    = (const float*)d_in[11];
  float* out = (float*)d_out;                      // (2048, 1024)

  char* ws = (char*)d_ws;
  // offsets (bytes)
  unsigned short* wqkv = (unsigned short*)(ws + 0);            // 5120x2048 bf16 = 20971520
  unsigned short* wo   = (unsigned short*)(ws + 20971520);     // 2048x2048 bf16 = 8388608
  unsigned short* xT   = (unsigned short*)(ws + 29360128);     // 1024x2048 bf16 = 4194304
  float* qkv_raw       = (float*)(ws + 33554432);              // 5120x1024 f32 = 20971520
  float* qn            = (float*)(ws + 54525952);              // 16x1024x128   = 8388608
  float* kn            = (float*)(ws + 62914560);              // 4x1024x128    = 2097152
  float* vtb           = (float*)(ws + 65011712);              // 4x1024x128    = 2097152
  float* sg            = (float*)(ws + 67108864);              // 16x1024x128   = 8388608
  unsigned short* aoT  = (unsigned short*)(ws + 75497472);     // 1024x2048 bf16= 4194304

  // 1. weight casts
  cast_bf16_kernel<<<(4096 * 2048 / 4 + 255) / 256, 256, 0, stream>>>(q_proj_w, wqkv, 4096 * 2048 / 4);
  cast_bf16_kernel<<<(512 * 2048 / 4 + 255) / 256, 256, 0, stream>>>(k_proj_w, wqkv + 4096 * 2048, 512 * 2048 / 4);
  cast_bf16_kernel<<<(512 * 2048 / 4 + 255) / 256, 256, 0, stream>>>(v_proj_w, wqkv + 4608 * 2048, 512 * 2048 / 4);
  cast_bf16_kernel<<<(2048 * 2048 / 4 + 255) / 256, 256, 0, stream>>>(o_proj_w, wo, 2048 * 2048 / 4);
  // 2. x transpose+cast
  transpose_cast_x_kernel<<<dim3(32, 64), 256, 0, stream>>>(hs, xT);
  // 3. fused QKV GEMM: (5120,2048)@(2048,1024) -> qkv_raw
  gemm_bt_kernel<<<dim3(8, 40), 256, 0, stream>>>(wqkv, xT, qkv_raw, 5120, 1024, 2048);
  // 4. norm + rope
  norm_rope_kernel<<<dim3(16, 16), 256, 0, stream>>>(qkv_raw, 256, q_norm_w, pos_ids, cos_c, sin_c, qn);
  norm_rope_kernel<<<dim3(4, 16), 256, 0, stream>>>(qkv_raw + (size_t)4096 * 1024, 128, k_norm_w, pos_ids, cos_c, sin_c, kn);
  // 5. v transpose; gate transpose + sigmoid
  transpose_head_kernel<<<dim3(32, 4, 4), 256, 0, stream>>>(qkv_raw + (size_t)4608 * 1024, 128, 0, 0, vtb);
  transpose_head_kernel<<<dim3(32, 4, 16), 256, 0, stream>>>(qkv_raw, 256, 128, 1, sg);
  // 6. attention (writes gated output transposed, bf16, as (S, H*D))
  attn_kernel<<<dim3(16, 64), 256, 0, stream>>>(qn, kn, vtb, sg, aoT);
  // 7. O-proj: (2048,2048)@(2048,1024) -> d_out
  gemm_bt_kernel<<<dim3(8, 16), 256, 0, stream>>>(wo, aoT, out, 2048, 1024, 2048);
}

// Round 2
// 312.998 us; speedup vs baseline: 1.3729x; 1.3729x over previous
//
#include <hip/hip_runtime.h>
#include <cstdint>

#define S_LEN 1024
#define C_DIM 2048
#define NH    16
#define NHK   4
#define HD    128
#define ROT   32
#define SCALE 0.08838834764831845f  // 1/sqrt(128)

typedef __bf16 bf16x8 __attribute__((ext_vector_type(8)));
typedef float floatx4 __attribute__((ext_vector_type(4)));
typedef unsigned short ushortx8 __attribute__((ext_vector_type(8)));

__device__ __forceinline__ unsigned short f2bf(float f) {
  union { float f; uint32_t u; } x; x.f = f;
  uint32_t r = (x.u + 0x7fffu + ((x.u >> 16) & 1u)) >> 16;
  return (unsigned short)r;
}

__device__ __forceinline__ void async_copy16(const unsigned short* g, unsigned short* l) {
  __builtin_amdgcn_global_load_lds(
      (const __attribute__((address_space(1))) void*)g,
      (__attribute__((address_space(3))) void*)l,
      16, 0, 0);
}

// ---------------- cast f32 -> bf16 (vectorized) ----------------
__global__ void cast_bf16_kernel(const float* __restrict__ in,
                                 unsigned short* __restrict__ out, int n4) {
  int i = blockIdx.x * blockDim.x + threadIdx.x;
  if (i >= n4) return;
  float4 v = ((const float4*)in)[i];
  ushort4 o;
  o.x = f2bf(v.x); o.y = f2bf(v.y); o.z = f2bf(v.z); o.w = f2bf(v.w);
  ((ushort4*)out)[i] = o;
}

// ---------------- transpose + cast x (C,S) -> xT (S,C) bf16 ----------------
__global__ __launch_bounds__(256)
void transpose_cast_x_kernel(const float* __restrict__ x, unsigned short* __restrict__ xT) {
  __shared__ float t[32][33];
  int st = blockIdx.x, ct = blockIdx.y;
  int c = threadIdx.x & 31, rq = threadIdx.x >> 5;
#pragma unroll
  for (int i = 0; i < 4; ++i) {
    int r = rq + i * 8;
    t[r][c] = x[(size_t)(ct * 32 + r) * S_LEN + st * 32 + c];
  }
  __syncthreads();
#pragma unroll
  for (int i = 0; i < 4; ++i) {
    int r = rq + i * 8;  // s within tile
    xT[(size_t)(st * 32 + r) * C_DIM + ct * 32 + c] = f2bf(t[c][r]);
  }
}

// ---------------- GEMM: C(M,N) f32 = A(M,K)bf16 @ BT(N,K)bf16^T ----------------
// 128x128 tile, BK=64, 4 waves each 64x64 (4x4 of 16x16x32 MFMA)
__global__ __launch_bounds__(256)
void gemm_bt_kernel(const unsigned short* __restrict__ A,
                    const unsigned short* __restrict__ BT,
                    float* __restrict__ C, int M, int N, int K) {
  __shared__ unsigned short Asm[128 * 64];
  __shared__ unsigned short Bsm[128 * 64];
  int tid = threadIdx.x;
  int wave = tid >> 6, lane = tid & 63;
  int m0 = blockIdx.y * 128, n0 = blockIdx.x * 128;
  int l16 = lane & 15, quad = lane >> 4;
  int wm = (wave & 1) * 64, wn = (wave >> 1) * 64;
  int srow = wave * 8 + (lane >> 3);   // staging row within 32-row chunk
  int scol = (lane & 7) * 8;           // staging element col (8 bf16 = 16B)
  const unsigned short* Ag = A + (size_t)m0 * K;
  const unsigned short* Bg = BT + (size_t)n0 * K;
  floatx4 acc[4][4];
#pragma unroll
  for (int mi = 0; mi < 4; ++mi)
#pragma unroll
    for (int ni = 0; ni < 4; ++ni) acc[mi][ni] = (floatx4)0.f;

  for (int kt = 0; kt < K; kt += 64) {
#pragma unroll
    for (int i = 0; i < 4; ++i) {
      async_copy16(Ag + (size_t)(i * 32 + srow) * K + kt + scol, Asm + (i * 32 + wave * 8) * 64);
      async_copy16(Bg + (size_t)(i * 32 + srow) * K + kt + scol, Bsm + (i * 32 + wave * 8) * 64);
    }
    __syncthreads();
#pragma unroll
    for (int kb = 0; kb < 2; ++kb) {
      bf16x8 af[4], bfr[4];
#pragma unroll
      for (int mi = 0; mi < 4; ++mi)
        af[mi] = *(const bf16x8*)&Asm[(wm + mi * 16 + l16) * 64 + kb * 32 + quad * 8];
#pragma unroll
      for (int ni = 0; ni < 4; ++ni)
        bfr[ni] = *(const bf16x8*)&Bsm[(wn + ni * 16 + l16) * 64 + kb * 32 + quad * 8];
#pragma unroll
      for (int mi = 0; mi < 4; ++mi)
#pragma unroll
        for (int ni = 0; ni < 4; ++ni)
          acc[mi][ni] = __builtin_amdgcn_mfma_f32_16x16x32_bf16(af[mi], bfr[ni], acc[mi][ni], 0, 0, 0);
    }
    __syncthreads();
  }
#pragma unroll
  for (int mi = 0; mi < 4; ++mi) {
#pragma unroll
    for (int r = 0; r < 4; ++r) {
      int row = m0 + wm + mi * 16 + quad * 4 + r;
      float* Cp = C + (size_t)row * N + n0 + wn;
#pragma unroll
      for (int ni = 0; ni < 4; ++ni)
        Cp[ni * 16 + l16] = acc[mi][ni][r];
    }
  }
}

// ---------------- RMSNorm + RoPE, transpose (rows,S) -> (h,S,D) bf16 ----------------
__global__ __launch_bounds__(256)
void norm_rope_kernel(const float* __restrict__ raw, int head_rows,
                      const float* __restrict__ w,
                      const int* __restrict__ pos_ids,
                      const float* __restrict__ cosc, const float* __restrict__ sinc,
                      unsigned short* __restrict__ out) {
  __shared__ float tile[128][65];
  __shared__ float psum[4][64];
  __shared__ float rnorm[64];
  int h = blockIdx.x, st = blockIdx.y;
  int s0 = st * 64;
  int tid = threadIdx.x;
  const float* base = raw + (size_t)(h * head_rows) * S_LEN + s0;
  {
    int so = tid & 63, dq = tid >> 6;
#pragma unroll
    for (int it = 0; it < 32; ++it) {
      int d = it * 4 + dq;
      tile[d][so] = base[(size_t)d * S_LEN + so];
    }
  }
  __syncthreads();
  {
    int s = tid & 63, part = tid >> 6;
    float sum = 0.f;
    for (int dd = 0; dd < 32; ++dd) {
      float v = tile[part * 32 + dd][s];
      sum += v * v;
    }
    psum[part][s] = sum;
  }
  __syncthreads();
  if (tid < 64) {
    float tot = psum[0][tid] + psum[1][tid] + psum[2][tid] + psum[3][tid];
    rnorm[tid] = rsqrtf(tot * (1.0f / 128.0f) + 1e-6f);
  }
  __syncthreads();
  {
    int d = tid & 127, sr = tid >> 7;
    float wd = 1.0f + w[d];
    int dp = (d < 16) ? d + 16 : d - 16;
    float wdp = (d < ROT) ? (1.0f + w[dp]) : 0.f;
    for (int it = 0; it < 32; ++it) {
      int s = it * 2 + sr;
      float r = rnorm[s];
      float val = tile[d][s] * r * wd;
      if (d < ROT) {
        int pos = pos_ids[s0 + s];
        float cv = cosc[pos * ROT + d];
        float sv = sinc[pos * ROT + d];
        float partner = tile[dp][s] * r * wdp;
        val = val * cv + ((d < 16) ? -partner : partner) * sv;
      }
      out[((size_t)(h * S_LEN + s0 + s)) * HD + d] = f2bf(val);
    }
  }
}

// ---------------- transpose (rows,S) -> (h,S,D), sigmoid ----------------
__global__ __launch_bounds__(256)
void transpose_head_kernel(const float* __restrict__ raw, int head_rows, int row_off,
                           int do_sigmoid, float* __restrict__ out) {
  __shared__ float t[32][33];
  int st = blockIdx.x;  // s tile
  int dt = blockIdx.y;  // d tile
  int h = blockIdx.z;
  int c = threadIdx.x & 31, rq = threadIdx.x >> 5;
  const float* base = raw + (size_t)(h * head_rows + row_off + dt * 32) * S_LEN + st * 32;
#pragma unroll
  for (int i = 0; i < 4; ++i) {
    int r = rq + i * 8;
    t[r][c] = base[(size_t)r * S_LEN + c];
  }
  __syncthreads();
#pragma unroll
  for (int i = 0; i < 4; ++i) {
    int r = rq + i * 8;  // s within tile
    float v = t[c][r];
    if (do_sigmoid) v = 1.0f / (1.0f + __expf(-v));
    out[((size_t)(h * S_LEN + st * 32 + r)) * HD + dt * 32 + c] = v;
  }
}

// ---------------- MFMA flash attention ----------------
// grid (NH, S/32), block 128 (2 waves). Wave w owns queries [qt*32 + w*16, +16).
// K-tiles of 64 keys. Q,K bf16 (h,S,D); V bf16 transposed (hk,D,S); gate f32 (h,S,D).
#define QT 32
__global__ __launch_bounds__(128)
void attn_mfma_kernel(const unsigned short* __restrict__ qb,
                      const unsigned short* __restrict__ kbuf,
                      const unsigned short* __restrict__ vTb,
                      const float* __restrict__ sg,
                      unsigned short* __restrict__ outT) {
  __shared__ unsigned short Qs[QT][136];   // pad: 272B stride, uniform banks
  __shared__ unsigned short Ks[64][136];
  __shared__ unsigned short Vs[128][72];   // V^T tile: [d][key]
  __shared__ unsigned short Ps[2][16][72]; // per-wave P in A-layout rows
  int h = blockIdx.x, qt = blockIdx.y;
  int s0 = qt * QT;
  int hk = h >> 2;
  int tid = threadIdx.x;
  int wave = tid >> 6, lane = tid & 63;
  int l16 = lane & 15, quad = lane >> 4;

  // stage Q (32 x 128)
  const unsigned short* qg = qb + ((size_t)h * S_LEN + s0) * HD;
#pragma unroll
  for (int p = 0; p < 4; ++p) {
    int idx = p * 128 + tid;
    int r = idx >> 4, c8 = (idx & 15) * 8;
    *(ushortx8*)&Qs[r][c8] = *(const ushortx8*)(qg + (size_t)r * HD + c8);
  }

  float m_r[4], l_r[4];
#pragma unroll
  for (int r = 0; r < 4; ++r) { m_r[r] = -1e30f; l_r[r] = 0.f; }
  floatx4 acc_o[8];
#pragma unroll
  for (int i = 0; i < 8; ++i) acc_o[i] = (floatx4)0.f;

  int srow_base = s0 + wave * 16 + quad * 4;
  int kend = s0 + QT;
  __syncthreads();

  for (int jt = 0; jt < kend; jt += 64) {
    // stage K tile (64 keys x 128 d)
    const unsigned short* kg = kbuf + ((size_t)hk * S_LEN + jt) * HD;
#pragma unroll
    for (int p = 0; p < 8; ++p) {
      int idx = p * 128 + tid;
      int r = idx >> 4, c8 = (idx & 15) * 8;
      *(ushortx8*)&Ks[r][c8] = *(const ushortx8*)(kg + (size_t)r * HD + c8);
    }
    // stage V^T tile (128 d x 64 keys)
    const unsigned short* vg = vTb + (size_t)hk * HD * S_LEN + jt;
#pragma unroll
    for (int p = 0; p < 8; ++p) {
      int idx = p * 128 + tid;
      int d = idx >> 3, c8 = (idx & 7) * 8;
      *(ushortx8*)&Vs[d][c8] = *(const ushortx8*)(vg + (size_t)d * S_LEN + c8);
    }
    __syncthreads();

    // QK^T: 16 queries x 64 keys per wave
    floatx4 acc_s[4];
#pragma unroll
    for (int ni = 0; ni < 4; ++ni) acc_s[ni] = (floatx4)0.f;
#pragma unroll
    for (int kb = 0; kb < 4; ++kb) {
      bf16x8 af = *(const bf16x8*)&Qs[wave * 16 + l16][kb * 32 + quad * 8];
#pragma unroll
      for (int ni = 0; ni < 4; ++ni) {
        bf16x8 bk = *(const bf16x8*)&Ks[ni * 16 + l16][kb * 32 + quad * 8];
        acc_s[ni] = __builtin_amdgcn_mfma_f32_16x16x32_bf16(af, bk, acc_s[ni], 0, 0, 0);
      }
    }

    // online softmax per row (row = quad*4 + r, owned by this quad's 16 lanes)
    float alpha[4];
#pragma unroll
    for (int r = 0; r < 4; ++r) {
      float scv[4];
      float mx = -1e30f;
#pragma unroll
      for (int ni = 0; ni < 4; ++ni) {
        int jg = jt + ni * 16 + l16;
        float sv = (jg <= srow_base + r) ? acc_s[ni][r] * SCALE : -1e30f;
        scv[ni] = sv;
        mx = fmaxf(mx, sv);
      }
#pragma unroll
      for (int off = 8; off; off >>= 1) mx = fmaxf(mx, __shfl_xor(mx, off, 16));
      float mnew = fmaxf(m_r[r], mx);
      float psv = 0.f;
#pragma unroll
      for (int ni = 0; ni < 4; ++ni) {
        float pv = (scv[ni] > -1e29f) ? __expf(scv[ni] - mnew) : 0.f;
        Ps[wave][quad * 4 + r][ni * 16 + l16] = f2bf(pv);
        psv += pv;
      }
#pragma unroll
      for (int off = 8; off; off >>= 1) psv += __shfl_xor(psv, off, 16);
      alpha[r] = __expf(m_r[r] - mnew);
      m_r[r] = mnew;
      l_r[r] = l_r[r] * alpha[r] + psv;
    }
    // rescale accumulator
#pragma unroll
    for (int ni2 = 0; ni2 < 8; ++ni2)
#pragma unroll
      for (int r = 0; r < 4; ++r) acc_o[ni2][r] *= alpha[r];
    __syncthreads();  // Ps visible (and cheap ordering point)

    // PV: P(16x64) @ V(64x128)
#pragma unroll
    for (int kb = 0; kb < 2; ++kb) {
      bf16x8 ap = *(const bf16x8*)&Ps[wave][l16][kb * 32 + quad * 8];
#pragma unroll
      for (int ni2 = 0; ni2 < 8; ++ni2) {
        bf16x8 bv = *(const bf16x8*)&Vs[ni2 * 16 + l16][kb * 32 + quad * 8];
        acc_o[ni2] = __builtin_amdgcn_mfma_f32_16x16x32_bf16(ap, bv, acc_o[ni2], 0, 0, 0);
      }
    }
    __syncthreads();  // done with Ks/Vs before next stage
  }

  // epilogue: normalize, gate, write (S, NH*D) bf16
#pragma unroll
  for (int r = 0; r < 4; ++r) {
    int s = srow_base + r;
    float inv = 1.0f / l_r[r];
    const float* sgp = sg + ((size_t)h * S_LEN + s) * HD;
    unsigned short* op = outT + (size_t)s * (NH * HD) + h * HD;
#pragma unroll
    for (int ni2 = 0; ni2 < 8; ++ni2) {
      int d = ni2 * 16 + l16;
      op[d] = f2bf(acc_o[ni2][r] * inv * sgp[d]);
    }
  }
}

// ---------------- host launch ----------------
extern "C" void kernel_launch(void* const* d_in, const int* in_sizes, int n_in,
                              void* d_out, int out_size, void* d_ws, size_t ws_size,
                              hipStream_t stream) {
  const float* hs       = (const float*)d_in[0];   // (C, S)
  const float* q_proj_w = (const float*)d_in[1];   // (4096, 2048)
  const float* k_proj_w = (const float*)d_in[2];   // (512, 2048)
  const float* v_proj_w = (const float*)d_in[3];   // (512, 2048)
  const float* o_proj_w = (const float*)d_in[4];   // (2048, 2048)
  const float* q_norm_w = (const float*)d_in[5];
  const float* k_norm_w = (const float*)d_in[6];
  const int*   pos_ids  = (const int*)d_in[9];
  const float* cos_c    = (const float*)d_in[10];
  const float* sin_c    = (const float*)d_in[11];
  float* out = (float*)d_out;                      // (2048, 1024)

  char* ws = (char*)d_ws;
  unsigned short* wqkv = (unsigned short*)(ws + 0);            // 5120x2048 bf16
  unsigned short* wo   = (unsigned short*)(ws + 20971520);     // 2048x2048 bf16
  unsigned short* xT   = (unsigned short*)(ws + 29360128);     // 1024x2048 bf16
  float* qkv_raw       = (float*)(ws + 33554432);              // 5120x1024 f32
  unsigned short* qb   = (unsigned short*)(ws + 54525952);     // 16x1024x128 bf16
  unsigned short* kbuf = (unsigned short*)(ws + 58720256);     // 4x1024x128 bf16
  unsigned short* vTb  = (unsigned short*)(ws + 59768832);     // 4x128x1024 bf16 (V^T)
  float* sg            = (float*)(ws + 60817408);              // 16x1024x128 f32
  unsigned short* aoT  = (unsigned short*)(ws + 69206016);     // 1024x2048 bf16

  // 1. weight casts
  cast_bf16_kernel<<<(4096 * 2048 / 4 + 255) / 256, 256, 0, stream>>>(q_proj_w, wqkv, 4096 * 2048 / 4);
  cast_bf16_kernel<<<(512 * 2048 / 4 + 255) / 256, 256, 0, stream>>>(k_proj_w, wqkv + 4096 * 2048, 512 * 2048 / 4);
  cast_bf16_kernel<<<(512 * 2048 / 4 + 255) / 256, 256, 0, stream>>>(v_proj_w, wqkv + 4608 * 2048, 512 * 2048 / 4);
  cast_bf16_kernel<<<(2048 * 2048 / 4 + 255) / 256, 256, 0, stream>>>(o_proj_w, wo, 2048 * 2048 / 4);
  // 2. x transpose+cast
  transpose_cast_x_kernel<<<dim3(32, 64), 256, 0, stream>>>(hs, xT);
  // 3. fused QKV GEMM: (5120,2048)@(2048,1024) -> qkv_raw
  gemm_bt_kernel<<<dim3(8, 40), 256, 0, stream>>>(wqkv, xT, qkv_raw, 5120, 1024, 2048);
  // 4. norm + rope -> bf16 (h,S,D)
  norm_rope_kernel<<<dim3(16, 16), 256, 0, stream>>>(qkv_raw, 256, q_norm_w, pos_ids, cos_c, sin_c, qb);
  norm_rope_kernel<<<dim3(4, 16), 256, 0, stream>>>(qkv_raw + (size_t)4096 * 1024, 128, k_norm_w, pos_ids, cos_c, sin_c, kbuf);
  // 5. V: raw layout (hk,D,S) is already V^T — just cast to bf16
  cast_bf16_kernel<<<(512 * 1024 / 4 + 255) / 256, 256, 0, stream>>>(qkv_raw + (size_t)4608 * 1024, vTb, 512 * 1024 / 4);
  //    gate transpose + sigmoid -> (h,S,D) f32
  transpose_head_kernel<<<dim3(32, 4, 16), 256, 0, stream>>>(qkv_raw, 256, 128, 1, sg);
  // 6. MFMA flash attention -> aoT (S, H*D) bf16
  attn_mfma_kernel<<<dim3(16, 32), 128, 0, stream>>>(qb, kbuf, vTb, sg, aoT);
  // 7. O-proj: (2048,2048)@(2048,1024) -> d_out
  gemm_bt_kernel<<<dim3(8, 16), 256, 0, stream>>>(wo, aoT, out, 2048, 1024, 2048);
}

// Round 3
// 253.285 us; speedup vs baseline: 1.6965x; 1.2358x over previous
//
#include <hip/hip_runtime.h>
#include <cstdint>

#define S_LEN 1024
#define C_DIM 2048
#define NH    16
#define NHK   4
#define HD    128
#define ROT   32
#define SCALE 0.08838834764831845f  // 1/sqrt(128)

typedef __bf16 bf16x8 __attribute__((ext_vector_type(8)));
typedef float floatx4 __attribute__((ext_vector_type(4)));
typedef unsigned short ushortx8 __attribute__((ext_vector_type(8)));

__device__ __forceinline__ unsigned short f2bf(float f) {
  union { float f; uint32_t u; } x; x.f = f;
  uint32_t r = (x.u + 0x7fffu + ((x.u >> 16) & 1u)) >> 16;
  return (unsigned short)r;
}
__device__ __forceinline__ float bf2f(unsigned short v) {
  union { uint32_t u; float f; } x; x.u = (uint32_t)v << 16; return x.f;
}

__device__ __forceinline__ void async_copy16(const unsigned short* g, unsigned short* l) {
  __builtin_amdgcn_global_load_lds(
      (const __attribute__((address_space(1))) void*)g,
      (__attribute__((address_space(3))) void*)l,
      16, 0, 0);
}

// ---------------- fused weight cast f32 -> bf16 (all 4 weights, 1 launch) ----
__global__ void cast_all_kernel(const float* __restrict__ qw, const float* __restrict__ kw,
                                const float* __restrict__ vw, const float* __restrict__ ow,
                                unsigned short* __restrict__ out) {
  const int NQ = 4096 * 2048 / 4, NK = 512 * 2048 / 4, NV = 512 * 2048 / 4;
  int i = blockIdx.x * blockDim.x + threadIdx.x;
  const float* src; int j;
  if (i < NQ) { src = qw; j = i; }
  else if (i < NQ + NK) { src = kw; j = i - NQ; }
  else if (i < NQ + NK + NV) { src = vw; j = i - NQ - NK; }
  else { src = ow; j = i - NQ - NK - NV; }
  float4 v = ((const float4*)src)[j];
  ushort4 o;
  o.x = f2bf(v.x); o.y = f2bf(v.y); o.z = f2bf(v.z); o.w = f2bf(v.w);
  ((ushort4*)out)[i] = o;
}

// ---------------- transpose + cast x (C,S) -> xT (S,C) bf16 ----------------
__global__ __launch_bounds__(256)
void transpose_cast_x_kernel(const float* __restrict__ x, unsigned short* __restrict__ xT) {
  __shared__ float t[32][33];
  int st = blockIdx.x, ct = blockIdx.y;
  int c = threadIdx.x & 31, rq = threadIdx.x >> 5;
#pragma unroll
  for (int i = 0; i < 4; ++i) {
    int r = rq + i * 8;
    t[r][c] = x[(size_t)(ct * 32 + r) * S_LEN + st * 32 + c];
  }
  __syncthreads();
#pragma unroll
  for (int i = 0; i < 4; ++i) {
    int r = rq + i * 8;  // s within tile
    xT[(size_t)(st * 32 + r) * C_DIM + ct * 32 + c] = f2bf(t[c][r]);
  }
}

// ---------------- RMSNorm + RoPE epilogue (q / k tiles) ----------------
// acc tile: row d = wm + mi*16 + quad*4 + r (0..127), col s = n0 + wn + ni*16 + l16
__device__ __forceinline__ void norm_rope_epilogue(
    floatx4 (&acc)[4][2], float (*pp)[2][16],
    const float* __restrict__ w, const int* __restrict__ pos_ids,
    const float* __restrict__ cosc, const float* __restrict__ sinc,
    unsigned short* __restrict__ outp,  // (S, D) for this head
    int wave, int lane, int wm, int wn, int n0) {
  int l16 = lane & 15, quad = lane >> 4;
#pragma unroll
  for (int ni = 0; ni < 2; ++ni) {
    float s = 0.f;
#pragma unroll
    for (int mi = 0; mi < 4; ++mi)
#pragma unroll
      for (int r = 0; r < 4; ++r) { float v = acc[mi][ni][r]; s += v * v; }
    s += __shfl_xor(s, 16);
    s += __shfl_xor(s, 32);
    if (quad == 0) pp[wave][ni][l16] = s;
  }
  __syncthreads();
  float rn[2];
#pragma unroll
  for (int ni = 0; ni < 2; ++ni)
    rn[ni] = rsqrtf((pp[wave][ni][l16] + pp[wave ^ 1][ni][l16]) * (1.0f / 128.0f) + 1e-6f);
#pragma unroll
  for (int ni = 0; ni < 2; ++ni) {
    int s = n0 + wn + ni * 16 + l16;
    int pos = pos_ids[s];
#pragma unroll
    for (int mi = 0; mi < 4; ++mi) {
      int dbase = wm + mi * 16 + quad * 4;
      ushort4 o;
#pragma unroll
      for (int r = 0; r < 4; ++r) {
        int d = dbase + r;
        float v = acc[mi][ni][r] * rn[ni] * (1.0f + w[d]);
        if (d < ROT) {  // uniform per (wm,mi) after unroll
          float cv = cosc[pos * ROT + d], sv = sinc[pos * ROT + d];
          int d2 = (d < 16) ? d + 16 : d - 16;
          float pv = acc[mi ^ 1][ni][r] * rn[ni] * (1.0f + w[d2]);
          v = v * cv + ((d < 16) ? -pv : pv) * sv;
        }
        ((unsigned short*)&o)[r] = f2bf(v);
      }
      *(ushort4*)&outp[(size_t)s * HD + dbase] = o;
    }
  }
}

// ---------------- QKV GEMM with fused norm/rope/sigmoid/cast epilogue -------
// A = wqkv (5120,2048) bf16, BT = xT (1024,2048) bf16. Tile 128(M) x 64(N), BK=64.
// 4 waves: wm=(wave&1)*64 (4 mi), wn=(wave>>1)*32 (2 ni). Grid (16, 40).
__global__ __launch_bounds__(256)
void gemm_qkv_fused(const unsigned short* __restrict__ A,
                    const unsigned short* __restrict__ BT,
                    const float* __restrict__ qw, const float* __restrict__ kw,
                    const int* __restrict__ pos_ids,
                    const float* __restrict__ cosc, const float* __restrict__ sinc,
                    unsigned short* __restrict__ qb, unsigned short* __restrict__ kbuf,
                    unsigned short* __restrict__ vTb, unsigned short* __restrict__ sgb) {
  __shared__ unsigned short Asm[128 * 64];
  __shared__ unsigned short Bsm[64 * 64];
  __shared__ float pp[4][2][16];
  int tid = threadIdx.x, wave = tid >> 6, lane = tid & 63;
  int l16 = lane & 15, quad = lane >> 4;
  int wm = (wave & 1) * 64, wn = (wave >> 1) * 32;
  int m0 = blockIdx.y * 128, n0 = blockIdx.x * 64;
  int srow = wave * 8 + (lane >> 3), scol = (lane & 7) * 8;
  const unsigned short* Ag = A + (size_t)m0 * C_DIM;
  const unsigned short* Bg = BT + (size_t)n0 * C_DIM;
  floatx4 acc[4][2];
#pragma unroll
  for (int mi = 0; mi < 4; ++mi)
#pragma unroll
    for (int ni = 0; ni < 2; ++ni) acc[mi][ni] = (floatx4)0.f;

  for (int kt = 0; kt < C_DIM; kt += 64) {
#pragma unroll
    for (int i = 0; i < 4; ++i)
      async_copy16(Ag + (size_t)(i * 32 + srow) * C_DIM + kt + scol, Asm + (i * 32 + wave * 8) * 64);
#pragma unroll
    for (int i = 0; i < 2; ++i)
      async_copy16(Bg + (size_t)(i * 32 + srow) * C_DIM + kt + scol, Bsm + (i * 32 + wave * 8) * 64);
    __syncthreads();
#pragma unroll
    for (int kb = 0; kb < 2; ++kb) {
      bf16x8 af[4], bfr[2];
#pragma unroll
      for (int mi = 0; mi < 4; ++mi)
        af[mi] = *(const bf16x8*)&Asm[(wm + mi * 16 + l16) * 64 + kb * 32 + quad * 8];
#pragma unroll
      for (int ni = 0; ni < 2; ++ni)
        bfr[ni] = *(const bf16x8*)&Bsm[(wn + ni * 16 + l16) * 64 + kb * 32 + quad * 8];
#pragma unroll
      for (int mi = 0; mi < 4; ++mi)
#pragma unroll
        for (int ni = 0; ni < 2; ++ni)
          acc[mi][ni] = __builtin_amdgcn_mfma_f32_16x16x32_bf16(af[mi], bfr[ni], acc[mi][ni], 0, 0, 0);
    }
    __syncthreads();
  }

  // ---- fused epilogue; tile type from blockIdx.y (block-uniform) ----
  int ty = blockIdx.y;
  if (ty < 32) {
    int h = ty >> 1;
    if ((ty & 1) == 0) {
      // q rows of head h: rmsnorm + rope -> qb (h,S,D)
      norm_rope_epilogue(acc, pp, qw, pos_ids, cosc, sinc,
                         qb + (size_t)h * S_LEN * HD, wave, lane, wm, wn, n0);
    } else {
      // gate rows: sigmoid -> sgb (h,S,D) bf16
#pragma unroll
      for (int ni = 0; ni < 2; ++ni) {
        int s = n0 + wn + ni * 16 + l16;
#pragma unroll
        for (int mi = 0; mi < 4; ++mi) {
          int dbase = wm + mi * 16 + quad * 4;
          ushort4 o;
#pragma unroll
          for (int r = 0; r < 4; ++r)
            ((unsigned short*)&o)[r] = f2bf(1.0f / (1.0f + __expf(-acc[mi][ni][r])));
          *(ushort4*)&sgb[((size_t)h * S_LEN + s) * HD + dbase] = o;
        }
      }
    }
  } else if (ty < 36) {
    int hk = ty - 32;  // k head: rmsnorm + rope -> kbuf (hk,S,D)
    norm_rope_epilogue(acc, pp, kw, pos_ids, cosc, sinc,
                       kbuf + (size_t)hk * S_LEN * HD, wave, lane, wm, wn, n0);
  } else {
    int hk = ty - 36;  // v head: rows are d, cols are s -> vTb (hk,D,S) bf16
#pragma unroll
    for (int mi = 0; mi < 4; ++mi)
#pragma unroll
      for (int r = 0; r < 4; ++r) {
        int d = wm + mi * 16 + quad * 4 + r;
        unsigned short* vp = vTb + (size_t)hk * HD * S_LEN + (size_t)d * S_LEN + n0 + wn;
#pragma unroll
        for (int ni = 0; ni < 2; ++ni)
          vp[ni * 16 + l16] = f2bf(acc[mi][ni][r]);
      }
  }
}

// ---------------- O-proj GEMM: C(2048,1024) f32 = wo(2048,2048) @ aoT^T ----
// Tile 64x64, BK=64, 4 waves each 32x32 (2x2 MFMA). Grid (16, 32) = 512 blocks.
__global__ __launch_bounds__(256)
void gemm_oproj_kernel(const unsigned short* __restrict__ A,
                       const unsigned short* __restrict__ BT,
                       float* __restrict__ C) {
  __shared__ unsigned short Asm[64 * 64];
  __shared__ unsigned short Bsm[64 * 64];
  int tid = threadIdx.x, wave = tid >> 6, lane = tid & 63;
  int l16 = lane & 15, quad = lane >> 4;
  int wm = (wave & 1) * 32, wn = (wave >> 1) * 32;
  int m0 = blockIdx.y * 64, n0 = blockIdx.x * 64;
  int srow = wave * 8 + (lane >> 3), scol = (lane & 7) * 8;
  const unsigned short* Ag = A + (size_t)m0 * C_DIM;
  const unsigned short* Bg = BT + (size_t)n0 * C_DIM;
  floatx4 acc[2][2];
#pragma unroll
  for (int mi = 0; mi < 2; ++mi)
#pragma unroll
    for (int ni = 0; ni < 2; ++ni) acc[mi][ni] = (floatx4)0.f;

  for (int kt = 0; kt < C_DIM; kt += 64) {
#pragma unroll
    for (int i = 0; i < 2; ++i) {
      async_copy16(Ag + (size_t)(i * 32 + srow) * C_DIM + kt + scol, Asm + (i * 32 + wave * 8) * 64);
      async_copy16(Bg + (size_t)(i * 32 + srow) * C_DIM + kt + scol, Bsm + (i * 32 + wave * 8) * 64);
    }
    __syncthreads();
#pragma unroll
    for (int kb = 0; kb < 2; ++kb) {
      bf16x8 af[2], bfr[2];
#pragma unroll
      for (int mi = 0; mi < 2; ++mi)
        af[mi] = *(const bf16x8*)&Asm[(wm + mi * 16 + l16) * 64 + kb * 32 + quad * 8];
#pragma unroll
      for (int ni = 0; ni < 2; ++ni)
        bfr[ni] = *(const bf16x8*)&Bsm[(wn + ni * 16 + l16) * 64 + kb * 32 + quad * 8];
#pragma unroll
      for (int mi = 0; mi < 2; ++mi)
#pragma unroll
        for (int ni = 0; ni < 2; ++ni)
          acc[mi][ni] = __builtin_amdgcn_mfma_f32_16x16x32_bf16(af[mi], bfr[ni], acc[mi][ni], 0, 0, 0);
    }
    __syncthreads();
  }
#pragma unroll
  for (int mi = 0; mi < 2; ++mi)
#pragma unroll
    for (int r = 0; r < 4; ++r) {
      int row = m0 + wm + mi * 16 + quad * 4 + r;
      float* Cp = C + (size_t)row * S_LEN + n0 + wn;
#pragma unroll
      for (int ni = 0; ni < 2; ++ni)
        Cp[ni * 16 + l16] = acc[mi][ni][r];
    }
}

// ---------------- MFMA flash attention ----------------
// grid (NH, S/32), block 128 (2 waves). Wave w owns queries [qt*32 + w*16, +16).
#define QT 32
__global__ __launch_bounds__(128)
void attn_mfma_kernel(const unsigned short* __restrict__ qb,
                      const unsigned short* __restrict__ kbuf,
                      const unsigned short* __restrict__ vTb,
                      const unsigned short* __restrict__ sgb,
                      unsigned short* __restrict__ outT) {
  __shared__ unsigned short Qs[QT][136];
  __shared__ unsigned short Ks[64][136];
  __shared__ unsigned short Vs[128][72];   // V^T tile: [d][key]
  __shared__ unsigned short Ps[2][16][72]; // per-wave P in A-layout rows
  int h = blockIdx.x, qt = blockIdx.y;
  int s0 = qt * QT;
  int hk = h >> 2;
  int tid = threadIdx.x;
  int wave = tid >> 6, lane = tid & 63;
  int l16 = lane & 15, quad = lane >> 4;

  const unsigned short* qg = qb + ((size_t)h * S_LEN + s0) * HD;
#pragma unroll
  for (int p = 0; p < 4; ++p) {
    int idx = p * 128 + tid;
    int r = idx >> 4, c8 = (idx & 15) * 8;
    *(ushortx8*)&Qs[r][c8] = *(const ushortx8*)(qg + (size_t)r * HD + c8);
  }

  float m_r[4], l_r[4];
#pragma unroll
  for (int r = 0; r < 4; ++r) { m_r[r] = -1e30f; l_r[r] = 0.f; }
  floatx4 acc_o[8];
#pragma unroll
  for (int i = 0; i < 8; ++i) acc_o[i] = (floatx4)0.f;

  int srow_base = s0 + wave * 16 + quad * 4;
  int kend = s0 + QT;
  __syncthreads();

  for (int jt = 0; jt < kend; jt += 64) {
    const unsigned short* kg = kbuf + ((size_t)hk * S_LEN + jt) * HD;
#pragma unroll
    for (int p = 0; p < 8; ++p) {
      int idx = p * 128 + tid;
      int r = idx >> 4, c8 = (idx & 15) * 8;
      *(ushortx8*)&Ks[r][c8] = *(const ushortx8*)(kg + (size_t)r * HD + c8);
    }
    const unsigned short* vg = vTb + (size_t)hk * HD * S_LEN + jt;
#pragma unroll
    for (int p = 0; p < 8; ++p) {
      int idx = p * 128 + tid;
      int d = idx >> 3, c8 = (idx & 7) * 8;
      *(ushortx8*)&Vs[d][c8] = *(const ushortx8*)(vg + (size_t)d * S_LEN + c8);
    }
    __syncthreads();

    floatx4 acc_s[4];
#pragma unroll
    for (int ni = 0; ni < 4; ++ni) acc_s[ni] = (floatx4)0.f;
#pragma unroll
    for (int kb = 0; kb < 4; ++kb) {
      bf16x8 af = *(const bf16x8*)&Qs[wave * 16 + l16][kb * 32 + quad * 8];
#pragma unroll
      for (int ni = 0; ni < 4; ++ni) {
        bf16x8 bk = *(const bf16x8*)&Ks[ni * 16 + l16][kb * 32 + quad * 8];
        acc_s[ni] = __builtin_amdgcn_mfma_f32_16x16x32_bf16(af, bk, acc_s[ni], 0, 0, 0);
      }
    }

    float alpha[4];
#pragma unroll
    for (int r = 0; r < 4; ++r) {
      float scv[4];
      float mx = -1e30f;
#pragma unroll
      for (int ni = 0; ni < 4; ++ni) {
        int jg = jt + ni * 16 + l16;
        float sv = (jg <= srow_base + r) ? acc_s[ni][r] * SCALE : -1e30f;
        scv[ni] = sv;
        mx = fmaxf(mx, sv);
      }
#pragma unroll
      for (int off = 8; off; off >>= 1) mx = fmaxf(mx, __shfl_xor(mx, off, 16));
      float mnew = fmaxf(m_r[r], mx);
      float psv = 0.f;
#pragma unroll
      for (int ni = 0; ni < 4; ++ni) {
        float pv = (scv[ni] > -1e29f) ? __expf(scv[ni] - mnew) : 0.f;
        Ps[wave][quad * 4 + r][ni * 16 + l16] = f2bf(pv);
        psv += pv;
      }
#pragma unroll
      for (int off = 8; off; off >>= 1) psv += __shfl_xor(psv, off, 16);
      alpha[r] = __expf(m_r[r] - mnew);
      m_r[r] = mnew;
      l_r[r] = l_r[r] * alpha[r] + psv;
    }
#pragma unroll
    for (int ni2 = 0; ni2 < 8; ++ni2)
#pragma unroll
      for (int r = 0; r < 4; ++r) acc_o[ni2][r] *= alpha[r];
    __syncthreads();

#pragma unroll
    for (int kb = 0; kb < 2; ++kb) {
      bf16x8 ap = *(const bf16x8*)&Ps[wave][l16][kb * 32 + quad * 8];
#pragma unroll
      for (int ni2 = 0; ni2 < 8; ++ni2) {
        bf16x8 bv = *(const bf16x8*)&Vs[ni2 * 16 + l16][kb * 32 + quad * 8];
        acc_o[ni2] = __builtin_amdgcn_mfma_f32_16x16x32_bf16(ap, bv, acc_o[ni2], 0, 0, 0);
      }
    }
    __syncthreads();
  }

#pragma unroll
  for (int r = 0; r < 4; ++r) {
    int s = srow_base + r;
    float inv = 1.0f / l_r[r];
    const unsigned short* sgp = sgb + ((size_t)h * S_LEN + s) * HD;
    unsigned short* op = outT + (size_t)s * (NH * HD) + h * HD;
#pragma unroll
    for (int ni2 = 0; ni2 < 8; ++ni2) {
      int d = ni2 * 16 + l16;
      op[d] = f2bf(acc_o[ni2][r] * inv * bf2f(sgp[d]));
    }
  }
}

// ---------------- host launch ----------------
extern "C" void kernel_launch(void* const* d_in, const int* in_sizes, int n_in,
                              void* d_out, int out_size, void* d_ws, size_t ws_size,
                              hipStream_t stream) {
  const float* hs       = (const float*)d_in[0];   // (C, S)
  const float* q_proj_w = (const float*)d_in[1];   // (4096, 2048)
  const float* k_proj_w = (const float*)d_in[2];   // (512, 2048)
  const float* v_proj_w = (const float*)d_in[3];   // (512, 2048)
  const float* o_proj_w = (const float*)d_in[4];   // (2048, 2048)
  const float* q_norm_w = (const float*)d_in[5];
  const float* k_norm_w = (const float*)d_in[6];
  const int*   pos_ids  = (const int*)d_in[9];
  const float* cos_c    = (const float*)d_in[10];
  const float* sin_c    = (const float*)d_in[11];
  float* out = (float*)d_out;                      // (2048, 1024)

  char* ws = (char*)d_ws;
  unsigned short* wqkv = (unsigned short*)(ws + 0);            // 5120x2048 bf16 (wo contiguous after)
  unsigned short* wo   = (unsigned short*)(ws + 20971520);     // 2048x2048 bf16
  unsigned short* xT   = (unsigned short*)(ws + 29360128);     // 1024x2048 bf16
  unsigned short* qb   = (unsigned short*)(ws + 33554432);     // 16x1024x128 bf16
  unsigned short* kbuf = (unsigned short*)(ws + 37748736);     // 4x1024x128 bf16
  unsigned short* vTb  = (unsigned short*)(ws + 38797312);     // 4x128x1024 bf16 (V^T)
  unsigned short* sgb  = (unsigned short*)(ws + 39845888);     // 16x1024x128 bf16 (sigmoid gate)
  unsigned short* aoT  = (unsigned short*)(ws + 44040192);     // 1024x2048 bf16

  // 1. all weight casts in one launch (q,k,v -> wqkv; o -> wo right after)
  cast_all_kernel<<<14336, 256, 0, stream>>>(q_proj_w, k_proj_w, v_proj_w, o_proj_w, wqkv);
  // 2. x transpose+cast
  transpose_cast_x_kernel<<<dim3(32, 64), 256, 0, stream>>>(hs, xT);
  // 3. QKV GEMM with fused rmsnorm/rope/sigmoid/cast epilogue
  gemm_qkv_fused<<<dim3(16, 40), 256, 0, stream>>>(wqkv, xT, q_norm_w, k_norm_w,
                                                   pos_ids, cos_c, sin_c,
                                                   qb, kbuf, vTb, sgb);
  // 4. MFMA flash attention -> aoT (S, H*D) bf16
  attn_mfma_kernel<<<dim3(16, 32), 128, 0, stream>>>(qb, kbuf, vTb, sgb, aoT);
  // 5. O-proj -> d_out
  gemm_oproj_kernel<<<dim3(16, 32), 256, 0, stream>>>(wo, aoT, out);
}